// Round 4
// baseline (672.458 us; speedup 1.0000x reference)
//
#include <hip/hip_runtime.h>
#include <cstdint>
#include <cstddef>

typedef __bf16 bf16;
typedef float  f32x4  __attribute__((ext_vector_type(4)));
typedef __bf16 bf16x8 __attribute__((ext_vector_type(8)));
typedef __bf16 bf16x4 __attribute__((ext_vector_type(4)));

// ---------------- K0: prep (slots copy + all weight transposes) ----------------
// WT[k][col] layouts so GEMM K-loops read weights lane-coalesced.
__global__ __launch_bounds__(256) void k_prep(
    const float* __restrict__ slots_in, const float* __restrict__ Wq,
    const float* __restrict__ Wv, const float* __restrict__ W_ih,
    const float* __restrict__ W_hh, const float* __restrict__ W1,
    const float* __restrict__ W2,
    float* __restrict__ slots, float* __restrict__ WqT, float* __restrict__ WvT,
    float* __restrict__ WihT, float* __restrict__ WhhT,
    float* __restrict__ W1T, float* __restrict__ W2T)
{
    const int i = blockIdx.x * 256 + threadIdx.x;
    if (i < 65536) { slots[i] = slots_in[i]; }
    else if (i < 131072) { int j = i - 65536;  WqT[j] = Wq[(j & 255)*256 + (j >> 8)]; }
    else if (i < 196608) { int j = i - 131072; WvT[j] = Wv[(j & 255)*256 + (j >> 8)]; }
    else if (i < 393216) { int j = i - 196608; int k = j/768, c = j - k*768; WihT[j] = W_ih[c*256 + k]; }
    else if (i < 589824) { int j = i - 393216; int k = j/768, c = j - k*768; WhhT[j] = W_hh[c*256 + k]; }
    else if (i < 720896) { int j = i - 589824; int k = j >> 9, c = j & 511; W1T[j] = W1[c*256 + k]; }
    else                 { int j = i - 720896; int k = j >> 8, c = j & 255; W2T[j] = W2[c*512 + k]; }
}

// ---------------- K1: LayerNorm(inputs) -> xln bf16 ----------------
__global__ __launch_bounds__(256) void k_ln_in(
    const float* __restrict__ x, const float* __restrict__ g,
    const float* __restrict__ b, bf16* __restrict__ xln)
{
    const int wave = threadIdx.x >> 6, lane = threadIdx.x & 63;
    const size_t row = (size_t)blockIdx.x * 4 + wave;
    const float* xr = x + row * 256 + lane * 4;
    f32x4 v = *(const f32x4*)xr;
    float s  = v[0] + v[1] + v[2] + v[3];
    float ss = v[0]*v[0] + v[1]*v[1] + v[2]*v[2] + v[3]*v[3];
#pragma unroll
    for (int m = 32; m >= 1; m >>= 1) { s += __shfl_xor(s, m); ss += __shfl_xor(ss, m); }
    const float mean = s * (1.f/256.f);
    const float var  = ss * (1.f/256.f) - mean*mean;
    const float rstd = rsqrtf(var + 1e-5f);
    const f32x4 gg = *(const f32x4*)(g + lane*4);
    const f32x4 bb = *(const f32x4*)(b + lane*4);
    bf16x4 o;
#pragma unroll
    for (int e = 0; e < 4; ++e) o[e] = (bf16)((v[e]-mean)*rstd*gg[e] + bb[e]);
    *(bf16x4*)(xln + row*256 + lane*4) = o;
}

// ---------------- K_q0: seed q2 for iteration 0 ----------------
__global__ __launch_bounds__(512) void k_q0(
    const float* __restrict__ slots, const float* __restrict__ WqT,
    const float* __restrict__ Wk, const float* __restrict__ g_s,
    const float* __restrict__ b_s, float* __restrict__ q2buf,
    float* __restrict__ den)
{
    const int b = blockIdx.x, tid = threadIdx.x;
    __shared__ float HS[2048], SLN[2048], Q[2048];
#pragma unroll
    for (int ii = 0; ii < 4; ++ii) {
        const int idx = ii*512 + tid;
        HS[idx] = slots[(size_t)b*2048 + idx];
    }
    if (tid < 8) den[b*8 + tid] = 0.f;
    __syncthreads();
    {   // LN_s: wave per slot
        const int s = tid >> 6, lane = tid & 63;
        const f32x4 v = *(const f32x4*)&HS[s*256 + lane*4];
        float s1 = v[0]+v[1]+v[2]+v[3];
        float s2 = v[0]*v[0]+v[1]*v[1]+v[2]*v[2]+v[3]*v[3];
#pragma unroll
        for (int m = 32; m >= 1; m >>= 1) { s1 += __shfl_xor(s1, m); s2 += __shfl_xor(s2, m); }
        const float mean = s1*(1.f/256.f);
        const float var  = s2*(1.f/256.f) - mean*mean;
        const float rstd = rsqrtf(var + 1e-5f);
        const f32x4 gv = *(const f32x4*)(g_s + lane*4);
        const f32x4 bv = *(const f32x4*)(b_s + lane*4);
#pragma unroll
        for (int e = 0; e < 4; ++e) SLN[s*256 + lane*4 + e] = (v[e]-mean)*rstd*gv[e] + bv[e];
    }
    __syncthreads();
    const int d = tid & 255, sp = tid >> 8;
    {   // q = sln@WqT * scale
        const float* wp = WqT + d;
        float ac[4] = {0,0,0,0};
        for (int k4 = 0; k4 < 64; ++k4) {
            const float w0 = wp[(k4*4+0)*256], w1 = wp[(k4*4+1)*256];
            const float w2 = wp[(k4*4+2)*256], w3 = wp[(k4*4+3)*256];
#pragma unroll
            for (int j = 0; j < 4; ++j) {
                const f32x4 h = *(const f32x4*)&SLN[(sp*4+j)*256 + k4*4];
                ac[j] += h[0]*w0 + h[1]*w1 + h[2]*w2 + h[3]*w3;
            }
        }
#pragma unroll
        for (int j = 0; j < 4; ++j) Q[(sp*4+j)*256 + d] = ac[j] * 0.0625f;
    }
    __syncthreads();
    {   // q2 = q@Wk
        const float* wp = Wk + d;
        float ac[4] = {0,0,0,0};
        for (int k4 = 0; k4 < 64; ++k4) {
            const float w0 = wp[(k4*4+0)*256], w1 = wp[(k4*4+1)*256];
            const float w2 = wp[(k4*4+2)*256], w3 = wp[(k4*4+3)*256];
#pragma unroll
            for (int j = 0; j < 4; ++j) {
                const f32x4 h = *(const f32x4*)&Q[(sp*4+j)*256 + k4*4];
                ac[j] += h[0]*w0 + h[1]*w1 + h[2]*w2 + h[3]*w3;
            }
        }
#pragma unroll
        for (int j = 0; j < 4; ++j) q2buf[(size_t)b*2048 + (sp*4+j)*256 + d] = ac[j];
    }
}

// ---------------- K_attn1: logits = q2·xln[t]; softmax over s; a->abuf ----------------
__global__ __launch_bounds__(256) void k_attn1(
    const bf16* __restrict__ xln, const float* __restrict__ q2buf,
    bf16* __restrict__ abuf, float* __restrict__ den,
    float* __restrict__ logits_out, int write_logits)
{
    const int chunk = blockIdx.x, b = blockIdx.y, tid = threadIdx.x;
    __shared__ __align__(16) float q2s[8][256];
    {
        f32x4 v0 = *(const f32x4*)(q2buf + (size_t)b*2048 + tid*8);
        f32x4 v1 = *(const f32x4*)(q2buf + (size_t)b*2048 + tid*8 + 4);
        *(f32x4*)&q2s[tid >> 5][(tid & 31)*8]     = v0;
        *(f32x4*)&q2s[tid >> 5][(tid & 31)*8 + 4] = v1;
    }
    __syncthreads();

    const int t = chunk*256 + tid;
    const bf16* xp = xln + (size_t)(b*4096 + t)*256;
    float acc[8] = {0,0,0,0,0,0,0,0};
    for (int c8 = 0; c8 < 32; ++c8) {
        bf16x8 x8 = *(const bf16x8*)(xp + c8*8);
        float xf[8];
#pragma unroll
        for (int e = 0; e < 8; ++e) xf[e] = (float)x8[e];
#pragma unroll
        for (int s = 0; s < 8; ++s) {
            f32x4 qa = *(const f32x4*)&q2s[s][c8*8];
            f32x4 qb = *(const f32x4*)&q2s[s][c8*8 + 4];
#pragma unroll
            for (int e = 0; e < 4; ++e) acc[s] += qa[e]*xf[e] + qb[e]*xf[4+e];
        }
    }
    float mx = acc[0];
#pragma unroll
    for (int s = 1; s < 8; ++s) mx = fmaxf(mx, acc[s]);
    float a[8], sum = 0.f;
#pragma unroll
    for (int s = 0; s < 8; ++s) { a[s] = expf(acc[s] - mx); sum += a[s]; }
    const float inv = 1.f/sum;
#pragma unroll
    for (int s = 0; s < 8; ++s) a[s] = a[s]*inv + 1e-8f;

#pragma unroll
    for (int s = 0; s < 8; ++s)
        abuf[(size_t)(b*8 + s)*4096 + t] = (bf16)a[s];
    if (write_logits) {
#pragma unroll
        for (int s = 0; s < 8; ++s)
            logits_out[(size_t)(b*8 + s)*4096 + t] = acc[s];
    }
#pragma unroll
    for (int s = 0; s < 8; ++s) {
        float v = a[s];
#pragma unroll
        for (int m = 32; m >= 1; m >>= 1) v += __shfl_xor(v, m);
        if ((tid & 63) == 0) atomicAdd(&den[b*8 + s], v);
    }
}

// ---------------- K_attn2: numpart[b][chunk][s][c] = sum_t a[s][t]*xln[t][c] ----------------
__global__ __launch_bounds__(256) void k_attn2(
    const bf16* __restrict__ xln, const bf16* __restrict__ abuf,
    float* __restrict__ numpart)
{
    const int chunk = blockIdx.x, b = blockIdx.y, tid = threadIdx.x;
    __shared__ float alds[8][132];
    for (int i = tid; i < 1024; i += 256)
        alds[i >> 7][i & 127] = (float)abuf[(size_t)(b*8 + (i >> 7))*4096 + chunk*128 + (i & 127)];
    __syncthreads();

    const int s2 = tid >> 5, u = tid & 31;
    float nacc[8] = {0,0,0,0,0,0,0,0};
    const bf16* xp = xln + (size_t)(b*4096 + chunk*128)*256 + u*8;
#pragma unroll 4
    for (int t = 0; t < 128; ++t) {
        bf16x8 x8 = *(const bf16x8*)(xp + (size_t)t*256);
        const float a = alds[s2][t];
#pragma unroll
        for (int j = 0; j < 8; ++j) nacc[j] += a * (float)x8[j];
    }
    float* np = numpart + ((size_t)(b*32 + chunk)*8 + s2)*256 + u*8;
    *(f32x4*)np       = (f32x4){nacc[0], nacc[1], nacc[2], nacc[3]};
    *(f32x4*)(np + 4) = (f32x4){nacc[4], nacc[5], nacc[6], nacc[7]};
}

// ---------------- K_attnsw: attn_sw = (softmax+eps)/den ----------------
__global__ __launch_bounds__(256) void k_attnsw(
    const float* __restrict__ logits, const float* __restrict__ den,
    float* __restrict__ attn_out)
{
    const int chunk = blockIdx.x, b = blockIdx.y;
    const int t = chunk*256 + threadIdx.x;
    float l[8];
#pragma unroll
    for (int s = 0; s < 8; ++s) l[s] = logits[(size_t)(b*8 + s)*4096 + t];
    float mx = l[0];
#pragma unroll
    for (int s = 1; s < 8; ++s) mx = fmaxf(mx, l[s]);
    float e[8], sum = 0.f;
#pragma unroll
    for (int s = 0; s < 8; ++s) { e[s] = expf(l[s] - mx); sum += e[s]; }
    const float inv = 1.f/sum;
#pragma unroll
    for (int s = 0; s < 8; ++s)
        attn_out[(size_t)(b*8 + s)*4096 + t] = (e[s]*inv + 1e-8f) / den[b*8 + s];
}

// ---------------- K_slot: upd -> gates -> GRU -> LN_m -> MLP -> slots' -> q2' ----------------
// grid 32 (one block per b), 512 threads. All intermediates in LDS (aliased).
__global__ __launch_bounds__(512) void k_slot(
    const float* __restrict__ numpart, float* __restrict__ den,
    float* __restrict__ slots,
    const float* __restrict__ WvT, const float* __restrict__ WihT,
    const float* __restrict__ WhhT,
    const float* __restrict__ b_ih, const float* __restrict__ b_hh,
    const float* __restrict__ g_m, const float* __restrict__ b_m,
    const float* __restrict__ W1T, const float* __restrict__ b1,
    const float* __restrict__ W2T, const float* __restrict__ b2,
    const float* __restrict__ WqT, const float* __restrict__ Wk,
    const float* __restrict__ g_s, const float* __restrict__ b_s,
    float* __restrict__ q2buf, float* __restrict__ out_slots, int last)
{
    const int b = blockIdx.x, tid = threadIdx.x;
    __shared__ __align__(16) float sm[14336];
    float* HS = sm;            // slots prev -> slots new
    float* B0 = sm + 2048;     // yn -> hpr
    float* B1 = sm + 4096;     // upd -> hln
    float* A1 = sm + 6144;     // hr -> gr -> sln
    float* A2 = sm + 8192;     // hz -> gz -> q
    float* A3 = sm + 10240;    // hn ; then hid[0:2048]
    float* A4 = sm + 12288;    // xn ; then hid[2048:4096]
    float* HID = A3;           // [8][512]
    __shared__ float dden[8];

    // Stage A: slots + yn(=sum numpart) + den
#pragma unroll
    for (int ii = 0; ii < 4; ++ii) {
        const int idx = ii*512 + tid;
        HS[idx] = slots[(size_t)b*2048 + idx];
        float a = 0.f;
        const float* np = numpart + (size_t)b*32*2048 + idx;
#pragma unroll 8
        for (int c = 0; c < 32; ++c) a += np[c*2048];
        B0[idx] = a;
    }
    if (tid < 8) dden[tid] = den[b*8 + tid];
    __syncthreads();
    if (tid < 8) den[b*8 + tid] = 0.f;

    const int d = tid & 255, sp = tid >> 8;

    // Stage gh: hr,hz,hn = HS@W_hh^T + b_hh -> A1,A2,A3
#pragma unroll
    for (int gg = 0; gg < 3; ++gg) {
        const int col = gg*256 + d;
        const float* wp = WhhT + col;
        float ac[4] = {0,0,0,0};
        for (int k4 = 0; k4 < 64; ++k4) {
            const float w0 = wp[(k4*4+0)*768], w1 = wp[(k4*4+1)*768];
            const float w2 = wp[(k4*4+2)*768], w3 = wp[(k4*4+3)*768];
#pragma unroll
            for (int j = 0; j < 4; ++j) {
                const f32x4 h = *(const f32x4*)&HS[(sp*4+j)*256 + k4*4];
                ac[j] += h[0]*w0 + h[1]*w1 + h[2]*w2 + h[3]*w3;
            }
        }
        const float bh = b_hh[col];
        float* dst = (gg == 0) ? A1 : (gg == 1) ? A2 : A3;
#pragma unroll
        for (int j = 0; j < 4; ++j) dst[(sp*4+j)*256 + d] = ac[j] + bh;
    }

    // Stage upd: upd = yn@Wv^T / den -> B1
    {
        const float* wp = WvT + d;
        float ac[4] = {0,0,0,0};
        for (int k4 = 0; k4 < 64; ++k4) {
            const float w0 = wp[(k4*4+0)*256], w1 = wp[(k4*4+1)*256];
            const float w2 = wp[(k4*4+2)*256], w3 = wp[(k4*4+3)*256];
#pragma unroll
            for (int j = 0; j < 4; ++j) {
                const f32x4 y = *(const f32x4*)&B0[(sp*4+j)*256 + k4*4];
                ac[j] += y[0]*w0 + y[1]*w1 + y[2]*w2 + y[3]*w3;
            }
        }
#pragma unroll
        for (int j = 0; j < 4; ++j) B1[(sp*4+j)*256 + d] = ac[j] / dden[sp*4+j];
    }
    __syncthreads();

    // Stage gx: xr,xz into A1,A2 (+=); xn -> A4
#pragma unroll
    for (int gg = 0; gg < 3; ++gg) {
        const int col = gg*256 + d;
        const float* wp = WihT + col;
        float ac[4] = {0,0,0,0};
        for (int k4 = 0; k4 < 64; ++k4) {
            const float w0 = wp[(k4*4+0)*768], w1 = wp[(k4*4+1)*768];
            const float w2 = wp[(k4*4+2)*768], w3 = wp[(k4*4+3)*768];
#pragma unroll
            for (int j = 0; j < 4; ++j) {
                const f32x4 u = *(const f32x4*)&B1[(sp*4+j)*256 + k4*4];
                ac[j] += u[0]*w0 + u[1]*w1 + u[2]*w2 + u[3]*w3;
            }
        }
        const float bi = b_ih[col];
        if (gg == 0) {
#pragma unroll
            for (int j = 0; j < 4; ++j) A1[(sp*4+j)*256 + d] += ac[j] + bi;
        } else if (gg == 1) {
#pragma unroll
            for (int j = 0; j < 4; ++j) A2[(sp*4+j)*256 + d] += ac[j] + bi;
        } else {
#pragma unroll
            for (int j = 0; j < 4; ++j) A4[(sp*4+j)*256 + d] = ac[j] + bi;
        }
    }
    __syncthreads();

    // Stage GRU: hpr -> B0
#pragma unroll
    for (int ii = 0; ii < 4; ++ii) {
        const int idx = ii*512 + tid;
        const float r = 1.f/(1.f + expf(-A1[idx]));
        const float z = 1.f/(1.f + expf(-A2[idx]));
        const float n = tanhf(A4[idx] + r*A3[idx]);
        B0[idx] = (1.f - z)*n + z*HS[idx];
    }
    __syncthreads();

    // Stage LN_m: hln -> B1 (wave per slot)
    {
        const int s = tid >> 6, lane = tid & 63;
        const f32x4 v = *(const f32x4*)&B0[s*256 + lane*4];
        float s1 = v[0]+v[1]+v[2]+v[3];
        float s2 = v[0]*v[0]+v[1]*v[1]+v[2]*v[2]+v[3]*v[3];
#pragma unroll
        for (int m = 32; m >= 1; m >>= 1) { s1 += __shfl_xor(s1, m); s2 += __shfl_xor(s2, m); }
        const float mean = s1*(1.f/256.f);
        const float var  = s2*(1.f/256.f) - mean*mean;
        const float rstd = rsqrtf(var + 1e-5f);
        const f32x4 gv = *(const f32x4*)(g_m + lane*4);
        const f32x4 bv = *(const f32x4*)(b_m + lane*4);
#pragma unroll
        for (int e = 0; e < 4; ++e)
            B1[s*256 + lane*4 + e] = (v[e]-mean)*rstd*gv[e] + bv[e];
    }
    __syncthreads();

    // Stage mlp1: hid = relu(hln@W1^T + b1) -> HID
    {
        const int col = tid;
        const float* wp = W1T + col;
        float ac[8] = {0,0,0,0,0,0,0,0};
        for (int k4 = 0; k4 < 64; ++k4) {
            const float w0 = wp[(k4*4+0)*512], w1 = wp[(k4*4+1)*512];
            const float w2 = wp[(k4*4+2)*512], w3 = wp[(k4*4+3)*512];
#pragma unroll
            for (int s = 0; s < 8; ++s) {
                const f32x4 h = *(const f32x4*)&B1[s*256 + k4*4];
                ac[s] += h[0]*w0 + h[1]*w1 + h[2]*w2 + h[3]*w3;
            }
        }
        const float bb = b1[col];
#pragma unroll
        for (int s = 0; s < 8; ++s) HID[s*512 + col] = fmaxf(ac[s] + bb, 0.f);
    }
    __syncthreads();

    // Stage mlp2: slots' = hpr + hid@W2^T + b2 -> HS + global
    {
        const float* wp = W2T + d;
        float ac[4] = {0,0,0,0};
        for (int k4 = 0; k4 < 128; ++k4) {
            const float w0 = wp[(k4*4+0)*256], w1 = wp[(k4*4+1)*256];
            const float w2 = wp[(k4*4+2)*256], w3 = wp[(k4*4+3)*256];
#pragma unroll
            for (int j = 0; j < 4; ++j) {
                const f32x4 h = *(const f32x4*)&HID[(sp*4+j)*512 + k4*4];
                ac[j] += h[0]*w0 + h[1]*w1 + h[2]*w2 + h[3]*w3;
            }
        }
        const float bb = b2[d];
#pragma unroll
        for (int j = 0; j < 4; ++j) {
            const int s = sp*4 + j;
            const float val = B0[s*256 + d] + ac[j] + bb;
            HS[s*256 + d] = val;
            slots[(size_t)b*2048 + s*256 + d] = val;
            if (last) out_slots[(size_t)b*2048 + s*256 + d] = val;
        }
    }
    __syncthreads();
    if (last) return;

    // Stage LN_s: sln -> A1
    {
        const int s = tid >> 6, lane = tid & 63;
        const f32x4 v = *(const f32x4*)&HS[s*256 + lane*4];
        float s1 = v[0]+v[1]+v[2]+v[3];
        float s2 = v[0]*v[0]+v[1]*v[1]+v[2]*v[2]+v[3]*v[3];
#pragma unroll
        for (int m = 32; m >= 1; m >>= 1) { s1 += __shfl_xor(s1, m); s2 += __shfl_xor(s2, m); }
        const float mean = s1*(1.f/256.f);
        const float var  = s2*(1.f/256.f) - mean*mean;
        const float rstd = rsqrtf(var + 1e-5f);
        const f32x4 gv = *(const f32x4*)(g_s + lane*4);
        const f32x4 bv = *(const f32x4*)(b_s + lane*4);
#pragma unroll
        for (int e = 0; e < 4; ++e)
            A1[s*256 + lane*4 + e] = (v[e]-mean)*rstd*gv[e] + bv[e];
    }
    __syncthreads();

    // Stage q: q = sln@Wq^T * scale -> A2
    {
        const float* wp = WqT + d;
        float ac[4] = {0,0,0,0};
        for (int k4 = 0; k4 < 64; ++k4) {
            const float w0 = wp[(k4*4+0)*256], w1 = wp[(k4*4+1)*256];
            const float w2 = wp[(k4*4+2)*256], w3 = wp[(k4*4+3)*256];
#pragma unroll
            for (int j = 0; j < 4; ++j) {
                const f32x4 h = *(const f32x4*)&A1[(sp*4+j)*256 + k4*4];
                ac[j] += h[0]*w0 + h[1]*w1 + h[2]*w2 + h[3]*w3;
            }
        }
#pragma unroll
        for (int j = 0; j < 4; ++j) A2[(sp*4+j)*256 + d] = ac[j] * 0.0625f;
    }
    __syncthreads();

    // Stage q2: q2 = q@Wk -> global
    {
        const float* wp = Wk + d;
        float ac[4] = {0,0,0,0};
        for (int k4 = 0; k4 < 64; ++k4) {
            const float w0 = wp[(k4*4+0)*256], w1 = wp[(k4*4+1)*256];
            const float w2 = wp[(k4*4+2)*256], w3 = wp[(k4*4+3)*256];
#pragma unroll
            for (int j = 0; j < 4; ++j) {
                const f32x4 h = *(const f32x4*)&A2[(sp*4+j)*256 + k4*4];
                ac[j] += h[0]*w0 + h[1]*w1 + h[2]*w2 + h[3]*w3;
            }
        }
#pragma unroll
        for (int j = 0; j < 4; ++j)
            q2buf[(size_t)b*2048 + (sp*4+j)*256 + d] = ac[j];
    }
}

// ---------------- host ----------------
extern "C" void kernel_launch(void* const* d_in, const int* in_sizes, int n_in,
                              void* d_out, int out_size, void* d_ws, size_t ws_size,
                              hipStream_t stream)
{
    const float* x        = (const float*)d_in[0];
    const float* slots_in = (const float*)d_in[1];
    const float* ln_in_g  = (const float*)d_in[2];
    const float* ln_in_b  = (const float*)d_in[3];
    const float* ln_s_g   = (const float*)d_in[4];
    const float* ln_s_b   = (const float*)d_in[5];
    const float* ln_m_g   = (const float*)d_in[6];
    const float* ln_m_b   = (const float*)d_in[7];
    const float* Wq       = (const float*)d_in[8];
    const float* Wk       = (const float*)d_in[9];
    const float* Wv       = (const float*)d_in[10];
    const float* W_ih     = (const float*)d_in[11];
    const float* W_hh     = (const float*)d_in[12];
    const float* b_ih     = (const float*)d_in[13];
    const float* b_hh     = (const float*)d_in[14];
    const float* W1       = (const float*)d_in[15];
    const float* b1       = (const float*)d_in[16];
    const float* W2       = (const float*)d_in[17];
    const float* b2       = (const float*)d_in[18];

    float* out_slots  = (float*)d_out;
    float* out_logits = out_slots + 65536;
    float* out_attn   = out_logits + 1048576;

    char* w = (char*)d_ws;
    bf16*  xln     = (bf16*)w;   w += 67108864;   // [131072][256] bf16
    float* q2buf   = (float*)w;  w += 262144;
    bf16*  abuf    = (bf16*)w;   w += 2097152;
    float* slots   = (float*)w;  w += 262144;
    float* WqT     = (float*)w;  w += 262144;
    float* WvT     = (float*)w;  w += 262144;
    float* WihT    = (float*)w;  w += 786432;
    float* WhhT    = (float*)w;  w += 786432;
    float* W1T     = (float*)w;  w += 524288;
    float* W2T     = (float*)w;  w += 524288;
    float* numpart = (float*)w;  w += 8388608;
    float* den     = (float*)w;  w += 4096;
    if ((size_t)(w - (char*)d_ws) > ws_size) return;  // ws too small: fail visibly

    k_prep<<<3328, 256, 0, stream>>>(slots_in, Wq, Wv, W_ih, W_hh, W1, W2,
                                     slots, WqT, WvT, WihT, WhhT, W1T, W2T);
    k_ln_in<<<32768, 256, 0, stream>>>(x, ln_in_g, ln_in_b, xln);
    k_q0<<<32, 512, 0, stream>>>(slots, WqT, Wk, ln_s_g, ln_s_b, q2buf, den);

    for (int it = 0; it < 3; ++it) {
        const int last = (it == 2);
        k_attn1<<<dim3(16, 32), 256, 0, stream>>>(xln, q2buf, abuf, den, out_logits, last);
        k_attn2<<<dim3(32, 32), 256, 0, stream>>>(xln, abuf, numpart);
        if (last)
            k_attnsw<<<dim3(16, 32), 256, 0, stream>>>(out_logits, den, out_attn);
        k_slot<<<32, 512, 0, stream>>>(numpart, den, slots,
                                       WvT, WihT, WhhT, b_ih, b_hh,
                                       ln_m_g, ln_m_b, W1T, b1, W2T, b2,
                                       WqT, Wk, ln_s_g, ln_s_b,
                                       q2buf, out_slots, last);
    }
}

// Round 5
// 593.104 us; speedup vs baseline: 1.1338x; 1.1338x over previous
//
#include <hip/hip_runtime.h>
#include <cstdint>
#include <cstddef>

typedef __bf16 bf16;
typedef float  f32x4  __attribute__((ext_vector_type(4)));
typedef __bf16 bf16x8 __attribute__((ext_vector_type(8)));
typedef __bf16 bf16x4 __attribute__((ext_vector_type(4)));

// ---------------- K0: prep (slots copy + all weight transposes) ----------------
// WT[k][col] layouts so GEMM K-loops read weights lane-coalesced.
__global__ __launch_bounds__(256) void k_prep(
    const float* __restrict__ slots_in, const float* __restrict__ Wq,
    const float* __restrict__ Wv, const float* __restrict__ W_ih,
    const float* __restrict__ W_hh, const float* __restrict__ W1,
    const float* __restrict__ W2,
    float* __restrict__ slots, float* __restrict__ WqT, float* __restrict__ WvT,
    float* __restrict__ WihT, float* __restrict__ WhhT,
    float* __restrict__ W1T, float* __restrict__ W2T)
{
    const int i = blockIdx.x * 256 + threadIdx.x;
    if (i < 65536) { slots[i] = slots_in[i]; }
    else if (i < 131072) { int j = i - 65536;  WqT[j] = Wq[(j & 255)*256 + (j >> 8)]; }
    else if (i < 196608) { int j = i - 131072; WvT[j] = Wv[(j & 255)*256 + (j >> 8)]; }
    else if (i < 393216) { int j = i - 196608; int k = j/768, c = j - k*768; WihT[j] = W_ih[c*256 + k]; }
    else if (i < 589824) { int j = i - 393216; int k = j/768, c = j - k*768; WhhT[j] = W_hh[c*256 + k]; }
    else if (i < 720896) { int j = i - 589824; int k = j >> 9, c = j & 511; W1T[j] = W1[c*256 + k]; }
    else                 { int j = i - 720896; int k = j >> 8, c = j & 255; W2T[j] = W2[c*512 + k]; }
}

// ---------------- K1: LayerNorm(inputs) -> xln bf16 ----------------
__global__ __launch_bounds__(256) void k_ln_in(
    const float* __restrict__ x, const float* __restrict__ g,
    const float* __restrict__ b, bf16* __restrict__ xln)
{
    const int wave = threadIdx.x >> 6, lane = threadIdx.x & 63;
    const size_t row = (size_t)blockIdx.x * 4 + wave;
    const float* xr = x + row * 256 + lane * 4;
    f32x4 v = *(const f32x4*)xr;
    float s  = v[0] + v[1] + v[2] + v[3];
    float ss = v[0]*v[0] + v[1]*v[1] + v[2]*v[2] + v[3]*v[3];
#pragma unroll
    for (int m = 32; m >= 1; m >>= 1) { s += __shfl_xor(s, m); ss += __shfl_xor(ss, m); }
    const float mean = s * (1.f/256.f);
    const float var  = ss * (1.f/256.f) - mean*mean;
    const float rstd = rsqrtf(var + 1e-5f);
    const f32x4 gg = *(const f32x4*)(g + lane*4);
    const f32x4 bb = *(const f32x4*)(b + lane*4);
    bf16x4 o;
#pragma unroll
    for (int e = 0; e < 4; ++e) o[e] = (bf16)((v[e]-mean)*rstd*gg[e] + bb[e]);
    *(bf16x4*)(xln + row*256 + lane*4) = o;
}

// ---------------- K_q0: seed q2 for iteration 0 (also zeroes den) ----------------
__global__ __launch_bounds__(512) void k_q0(
    const float* __restrict__ slots, const float* __restrict__ WqT,
    const float* __restrict__ Wk, const float* __restrict__ g_s,
    const float* __restrict__ b_s, float* __restrict__ q2buf,
    float* __restrict__ den)
{
    const int b = blockIdx.x, tid = threadIdx.x;
    __shared__ float HS[2048], SLN[2048], Q[2048];
#pragma unroll
    for (int ii = 0; ii < 4; ++ii) {
        const int idx = ii*512 + tid;
        HS[idx] = slots[(size_t)b*2048 + idx];
    }
    if (tid < 8) den[b*8 + tid] = 0.f;
    __syncthreads();
    {   // LN_s: wave per slot
        const int s = tid >> 6, lane = tid & 63;
        const f32x4 v = *(const f32x4*)&HS[s*256 + lane*4];
        float s1 = v[0]+v[1]+v[2]+v[3];
        float s2 = v[0]*v[0]+v[1]*v[1]+v[2]*v[2]+v[3]*v[3];
#pragma unroll
        for (int m = 32; m >= 1; m >>= 1) { s1 += __shfl_xor(s1, m); s2 += __shfl_xor(s2, m); }
        const float mean = s1*(1.f/256.f);
        const float var  = s2*(1.f/256.f) - mean*mean;
        const float rstd = rsqrtf(var + 1e-5f);
        const f32x4 gv = *(const f32x4*)(g_s + lane*4);
        const f32x4 bv = *(const f32x4*)(b_s + lane*4);
#pragma unroll
        for (int e = 0; e < 4; ++e) SLN[s*256 + lane*4 + e] = (v[e]-mean)*rstd*gv[e] + bv[e];
    }
    __syncthreads();
    const int d = tid & 255, sp = tid >> 8;
    {   // q = sln@WqT * scale
        const float* wp = WqT + d;
        float ac[4] = {0,0,0,0};
        for (int k4 = 0; k4 < 64; ++k4) {
            const float w0 = wp[(k4*4+0)*256], w1 = wp[(k4*4+1)*256];
            const float w2 = wp[(k4*4+2)*256], w3 = wp[(k4*4+3)*256];
#pragma unroll
            for (int j = 0; j < 4; ++j) {
                const f32x4 h = *(const f32x4*)&SLN[(sp*4+j)*256 + k4*4];
                ac[j] += h[0]*w0 + h[1]*w1 + h[2]*w2 + h[3]*w3;
            }
        }
#pragma unroll
        for (int j = 0; j < 4; ++j) Q[(sp*4+j)*256 + d] = ac[j] * 0.0625f;
    }
    __syncthreads();
    {   // q2 = q@Wk
        const float* wp = Wk + d;
        float ac[4] = {0,0,0,0};
        for (int k4 = 0; k4 < 64; ++k4) {
            const float w0 = wp[(k4*4+0)*256], w1 = wp[(k4*4+1)*256];
            const float w2 = wp[(k4*4+2)*256], w3 = wp[(k4*4+3)*256];
#pragma unroll
            for (int j = 0; j < 4; ++j) {
                const f32x4 h = *(const f32x4*)&Q[(sp*4+j)*256 + k4*4];
                ac[j] += h[0]*w0 + h[1]*w1 + h[2]*w2 + h[3]*w3;
            }
        }
#pragma unroll
        for (int j = 0; j < 4; ++j) q2buf[(size_t)b*2048 + (sp*4+j)*256 + d] = ac[j];
    }
}

// ---------------- K_attn: fused logits+softmax+num-partials over one xln pass ----
// grid (64 chunks of 64 tokens, 32 b), 256 threads. xln tile staged in LDS
// with XOR swizzle (slot ^= row&31 on 16B chunks) -> conflict-free b128 reads.
__global__ __launch_bounds__(256) void k_attn(
    const bf16* __restrict__ xln, const float* __restrict__ q2buf,
    float* __restrict__ numpart, float* __restrict__ den,
    float* __restrict__ logits_out, int write_logits)
{
    const int chunk = blockIdx.x;  // 0..63
    const int b     = blockIdx.y;  // 0..31
    const int tid   = threadIdx.x;
    __shared__ __align__(16) bf16  xs[64*256];      // 32 KB, swizzled
    __shared__ __align__(16) float q2s[8][256];     // 8 KB
    __shared__ float part[4][64][9];                // padded: conflict-free
    __shared__ float asmem[8][64];                  // 2 KB

    // stage xln tile (32 KB contiguous) into swizzled LDS
    {
        const bf16* src = xln + (size_t)(b*4096 + chunk*64)*256;
#pragma unroll
        for (int k = 0; k < 8; ++k) {
            const int i = k*256 + tid;          // 16B-chunk id 0..2047
            const int row = i >> 5, slot = i & 31;
            bf16x8 v = *(const bf16x8*)(src + (size_t)i*8);
            *(bf16x8*)((char*)xs + row*512 + ((slot ^ (row & 31)) << 4)) = v;
        }
        for (int i = tid; i < 2048; i += 256)
            q2s[i >> 8][i & 255] = q2buf[(size_t)b*2048 + i];
    }
    __syncthreads();

    // phase 1: logits. thread (q = dim-quarter, tok): partial dot over 64 dims.
    {
        const int q = tid >> 6, tok = tid & 63;
        float acc[8] = {0,0,0,0,0,0,0,0};
#pragma unroll
        for (int c8 = 0; c8 < 8; ++c8) {
            const int colb = (q*64 + c8*8)*2;
            bf16x8 x8 = *(const bf16x8*)((char*)xs + tok*512 + (colb ^ ((tok & 31) << 4)));
            float xf[8];
#pragma unroll
            for (int e = 0; e < 8; ++e) xf[e] = (float)x8[e];
#pragma unroll
            for (int s = 0; s < 8; ++s) {
                f32x4 qa = *(const f32x4*)&q2s[s][q*64 + c8*8];
                f32x4 qb = *(const f32x4*)&q2s[s][q*64 + c8*8 + 4];
#pragma unroll
                for (int e = 0; e < 4; ++e) acc[s] += qa[e]*xf[e] + qb[e]*xf[4+e];
            }
        }
#pragma unroll
        for (int s = 0; s < 8; ++s) part[q][tok][s] = acc[s];
    }
    __syncthreads();

    // softmax over slots (wave 0, one lane per token) + den atomics
    if (tid < 64) {
        const int tok = tid;
        float l[8];
#pragma unroll
        for (int s = 0; s < 8; ++s)
            l[s] = part[0][tok][s] + part[1][tok][s] + part[2][tok][s] + part[3][tok][s];
        float mx = l[0];
#pragma unroll
        for (int s = 1; s < 8; ++s) mx = fmaxf(mx, l[s]);
        float a[8], sum = 0.f;
#pragma unroll
        for (int s = 0; s < 8; ++s) { a[s] = expf(l[s] - mx); sum += a[s]; }
        const float inv = 1.f/sum;
#pragma unroll
        for (int s = 0; s < 8; ++s) { a[s] = a[s]*inv + 1e-8f; asmem[s][tok] = a[s]; }
        if (write_logits) {
#pragma unroll
            for (int s = 0; s < 8; ++s)
                logits_out[(size_t)(b*8 + s)*4096 + chunk*64 + tok] = l[s];
        }
#pragma unroll
        for (int s = 0; s < 8; ++s) {
            float v = a[s];
#pragma unroll
            for (int m = 32; m >= 1; m >>= 1) v += __shfl_xor(v, m);
            if (tok == 0) atomicAdd(&den[b*8 + s], v);
        }
    }
    __syncthreads();

    // phase 2: numpart[s][c] = sum_t a[s][t] * xln[t][c]
    {
        const int s2 = tid >> 5, u = tid & 31;
        float nacc[8] = {0,0,0,0,0,0,0,0};
        for (int t = 0; t < 64; ++t) {
            const float a = asmem[s2][t];
            bf16x8 x8 = *(const bf16x8*)((char*)xs + t*512 + ((u*16) ^ ((t & 31) << 4)));
#pragma unroll
            for (int j = 0; j < 8; ++j) nacc[j] += a * (float)x8[j];
        }
        float* np = numpart + (((size_t)b*64 + chunk)*8 + s2)*256 + u*8;
        *(f32x4*)np       = (f32x4){nacc[0], nacc[1], nacc[2], nacc[3]};
        *(f32x4*)(np + 4) = (f32x4){nacc[4], nacc[5], nacc[6], nacc[7]};
    }
}

// ---------------- K_attnsw: attn_sw = (softmax+eps)/den ----------------
__global__ __launch_bounds__(256) void k_attnsw(
    const float* __restrict__ logits, const float* __restrict__ den,
    float* __restrict__ attn_out)
{
    const int chunk = blockIdx.x, b = blockIdx.y;
    const int t = chunk*256 + threadIdx.x;
    float l[8];
#pragma unroll
    for (int s = 0; s < 8; ++s) l[s] = logits[(size_t)(b*8 + s)*4096 + t];
    float mx = l[0];
#pragma unroll
    for (int s = 1; s < 8; ++s) mx = fmaxf(mx, l[s]);
    float e[8], sum = 0.f;
#pragma unroll
    for (int s = 0; s < 8; ++s) { e[s] = expf(l[s] - mx); sum += e[s]; }
    const float inv = 1.f/sum;
#pragma unroll
    for (int s = 0; s < 8; ++s)
        attn_out[(size_t)(b*8 + s)*4096 + t] = (e[s]*inv + 1e-8f) / den[b*8 + s];
}

// ---------------- K_slot: one block per (b,s) row; whole slot chain in LDS ----
// grid 256, 512 threads (1 block/CU, 8 waves/CU).
__global__ __launch_bounds__(512) void k_slot(
    const float* __restrict__ numpart, float* __restrict__ den,
    float* __restrict__ slots,
    const float* __restrict__ WvT, const float* __restrict__ WihT,
    const float* __restrict__ WhhT,
    const float* __restrict__ b_ih, const float* __restrict__ b_hh,
    const float* __restrict__ g_m, const float* __restrict__ b_m,
    const float* __restrict__ W1T, const float* __restrict__ b1,
    const float* __restrict__ W2T, const float* __restrict__ b2,
    const float* __restrict__ WqT, const float* __restrict__ Wk,
    const float* __restrict__ g_s, const float* __restrict__ b_s,
    float* __restrict__ q2buf, float* __restrict__ out_slots, int last)
{
    const int bs = blockIdx.x;         // 0..255 = b*8+s
    const int b  = bs >> 3, s = bs & 7;
    const int tid = threadIdx.x;
    const int d = tid & 255, h = tid >> 8;

    __shared__ __align__(16) float HS[256], yn[256], upd[256], G[6][256];
    __shared__ __align__(16) float hpr[256], hln[256], hid[512], sln[256], qv[256];
    __shared__ __align__(16) float pp[2][256];
    __shared__ float red[8], dsc;

    // stage A: yn = sum_c numpart ; HS ; den snapshot+clear
    {
        float a = 0.f;
        const float* np = numpart + (((size_t)b*64 + h*32)*8 + s)*256 + d;
#pragma unroll 8
        for (int c = 0; c < 32; ++c) a += np[(size_t)c*2048];
        pp[h][d] = a;
        if (tid < 256) HS[tid] = slots[(size_t)bs*256 + tid];
        if (tid == 0) { dsc = den[bs]; den[bs] = 0.f; }
    }
    __syncthreads();
    if (tid < 256) yn[d] = pp[0][d] + pp[1][d];
    __syncthreads();

    // upd = (yn @ Wv^T) / den   (2-way k-split)
    {
        const float* wp = WvT + (size_t)(h*128)*256 + d;
        const float* yp = yn + h*128;
        float a = 0.f;
#pragma unroll 8
        for (int k = 0; k < 128; ++k) a += yp[k] * wp[(size_t)k*256];
        pp[h][d] = a;
    }
    __syncthreads();
    if (tid < 256) upd[d] = (pp[0][d] + pp[1][d]) / dsc;
    __syncthreads();

    // gates: 6 x 256-col dots (3 passes x 512 threads, full k=256)
#pragma unroll
    for (int p = 0; p < 3; ++p) {
        const int cg = p*512 + tid;            // 0..1535
        const int g = cg >> 8, dd = cg & 255;  // g: 0,1 | 2,3 | 4,5
        const float* src = (g < 3) ? upd : HS;
        const int col = (g % 3)*256 + dd;
        const float* wp = ((g < 3) ? WihT : WhhT) + col;
        float a = (g < 3) ? b_ih[col] : b_hh[col];
#pragma unroll 8
        for (int k = 0; k < 256; ++k) a += src[k] * wp[(size_t)k*768];
        G[g][dd] = a;
    }
    __syncthreads();

    // GRU
    if (tid < 256) {
        const float r = 1.f/(1.f + expf(-(G[0][d] + G[3][d])));
        const float z = 1.f/(1.f + expf(-(G[1][d] + G[4][d])));
        const float n = tanhf(G[2][d] + r*G[5][d]);
        hpr[d] = (1.f - z)*n + z*HS[d];
    }
    __syncthreads();

    // LN_m
    if (tid < 256) {
        const float v = hpr[d];
        float s1 = v, s2 = v*v;
#pragma unroll
        for (int m = 32; m >= 1; m >>= 1) { s1 += __shfl_xor(s1, m); s2 += __shfl_xor(s2, m); }
        if ((tid & 63) == 0) { red[tid >> 6] = s1; red[4 + (tid >> 6)] = s2; }
    }
    __syncthreads();
    if (tid < 256) {
        const float tot  = red[0]+red[1]+red[2]+red[3];
        const float tot2 = red[4]+red[5]+red[6]+red[7];
        const float mean = tot*(1.f/256.f);
        const float var  = tot2*(1.f/256.f) - mean*mean;
        const float rstd = rsqrtf(var + 1e-5f);
        hln[d] = (hpr[d]-mean)*rstd*g_m[d] + b_m[d];
    }
    __syncthreads();

    // mlp1: hid[512]
    {
        const float* wp = W1T + tid;
        float a = b1[tid];
#pragma unroll 8
        for (int k = 0; k < 256; ++k) a += hln[k] * wp[(size_t)k*512];
        hid[tid] = fmaxf(a, 0.f);
    }
    __syncthreads();

    // mlp2 (k=512, 2-way split) + residual
    {
        const float* wp = W2T + (size_t)(h*256)*256 + d;
        const float* hp = hid + h*256;
        float a = 0.f;
#pragma unroll 8
        for (int k = 0; k < 256; ++k) a += hp[k] * wp[(size_t)k*256];
        pp[h][d] = a;
    }
    __syncthreads();
    if (tid < 256) {
        const float val = hpr[d] + pp[0][d] + pp[1][d] + b2[d];
        HS[d] = val;
        slots[(size_t)bs*256 + d] = val;
        if (last) out_slots[(size_t)bs*256 + d] = val;
    }
    __syncthreads();
    if (last) return;

    // LN_s
    if (tid < 256) {
        const float v = HS[d];
        float s1 = v, s2 = v*v;
#pragma unroll
        for (int m = 32; m >= 1; m >>= 1) { s1 += __shfl_xor(s1, m); s2 += __shfl_xor(s2, m); }
        if ((tid & 63) == 0) { red[tid >> 6] = s1; red[4 + (tid >> 6)] = s2; }
    }
    __syncthreads();
    if (tid < 256) {
        const float tot  = red[0]+red[1]+red[2]+red[3];
        const float tot2 = red[4]+red[5]+red[6]+red[7];
        const float mean = tot*(1.f/256.f);
        const float var  = tot2*(1.f/256.f) - mean*mean;
        const float rstd = rsqrtf(var + 1e-5f);
        sln[d] = (HS[d]-mean)*rstd*g_s[d] + b_s[d];
    }
    __syncthreads();

    // q = sln @ Wq^T * scale (k-split)
    {
        const float* wp = WqT + (size_t)(h*128)*256 + d;
        const float* sp = sln + h*128;
        float a = 0.f;
#pragma unroll 8
        for (int k = 0; k < 128; ++k) a += sp[k] * wp[(size_t)k*256];
        pp[h][d] = a;
    }
    __syncthreads();
    if (tid < 256) qv[d] = (pp[0][d] + pp[1][d]) * 0.0625f;
    __syncthreads();

    // q2 = q @ Wk (k-split; Wk native [d][c] layout)
    {
        const float* wp = Wk + (size_t)(h*128)*256 + d;
        const float* qp = qv + h*128;
        float a = 0.f;
#pragma unroll 8
        for (int k = 0; k < 128; ++k) a += qp[k] * wp[(size_t)k*256];
        pp[h][d] = a;
    }
    __syncthreads();
    if (tid < 256) q2buf[(size_t)bs*256 + d] = pp[0][d] + pp[1][d];
}

// ---------------- host ----------------
extern "C" void kernel_launch(void* const* d_in, const int* in_sizes, int n_in,
                              void* d_out, int out_size, void* d_ws, size_t ws_size,
                              hipStream_t stream)
{
    const float* x        = (const float*)d_in[0];
    const float* slots_in = (const float*)d_in[1];
    const float* ln_in_g  = (const float*)d_in[2];
    const float* ln_in_b  = (const float*)d_in[3];
    const float* ln_s_g   = (const float*)d_in[4];
    const float* ln_s_b   = (const float*)d_in[5];
    const float* ln_m_g   = (const float*)d_in[6];
    const float* ln_m_b   = (const float*)d_in[7];
    const float* Wq       = (const float*)d_in[8];
    const float* Wk       = (const float*)d_in[9];
    const float* Wv       = (const float*)d_in[10];
    const float* W_ih     = (const float*)d_in[11];
    const float* W_hh     = (const float*)d_in[12];
    const float* b_ih     = (const float*)d_in[13];
    const float* b_hh     = (const float*)d_in[14];
    const float* W1       = (const float*)d_in[15];
    const float* b1       = (const float*)d_in[16];
    const float* W2       = (const float*)d_in[17];
    const float* b2       = (const float*)d_in[18];

    float* out_slots  = (float*)d_out;
    float* out_logits = out_slots + 65536;
    float* out_attn   = out_logits + 1048576;

    char* w = (char*)d_ws;
    bf16*  xln     = (bf16*)w;   w += 67108864;   // [131072][256] bf16
    float* q2buf   = (float*)w;  w += 262144;
    float* slots   = (float*)w;  w += 262144;
    float* WqT     = (float*)w;  w += 262144;
    float* WvT     = (float*)w;  w += 262144;
    float* WihT    = (float*)w;  w += 786432;
    float* WhhT    = (float*)w;  w += 786432;
    float* W1T     = (float*)w;  w += 524288;
    float* W2T     = (float*)w;  w += 524288;
    float* numpart = (float*)w;  w += 16777216;   // [32 b][64 chunk][8 s][256 c] f32
    float* den     = (float*)w;  w += 4096;
    if ((size_t)(w - (char*)d_ws) > ws_size) return;  // ws too small: fail visibly

    k_prep<<<3328, 256, 0, stream>>>(slots_in, Wq, Wv, W_ih, W_hh, W1, W2,
                                     slots, WqT, WvT, WihT, WhhT, W1T, W2T);
    k_ln_in<<<32768, 256, 0, stream>>>(x, ln_in_g, ln_in_b, xln);
    k_q0<<<32, 512, 0, stream>>>(slots, WqT, Wk, ln_s_g, ln_s_b, q2buf, den);

    for (int it = 0; it < 3; ++it) {
        const int last = (it == 2);
        k_attn<<<dim3(64, 32), 256, 0, stream>>>(xln, q2buf, numpart, den, out_logits, last);
        if (last)
            k_attnsw<<<dim3(16, 32), 256, 0, stream>>>(out_logits, den, out_attn);
        k_slot<<<256, 512, 0, stream>>>(numpart, den, slots,
                                        WvT, WihT, WhhT, b_ih, b_hh,
                                        ln_m_g, ln_m_b, W1T, b1, W2T, b2,
                                        WqT, Wk, ln_s_g, ln_s_b,
                                        q2buf, out_slots, last);
    }
}

// Round 6
// 449.154 us; speedup vs baseline: 1.4972x; 1.3205x over previous
//
#include <hip/hip_runtime.h>
#include <cstdint>
#include <cstddef>

typedef __bf16 bf16;
typedef float  f32x4  __attribute__((ext_vector_type(4)));
typedef __bf16 bf16x8 __attribute__((ext_vector_type(8)));
typedef __bf16 bf16x4 __attribute__((ext_vector_type(4)));

// padded-LDS helpers: 256-float vector stored as 16 groups of (16 data + 4 pad)
#define PSTORE(P, idx, val) (P)[(((idx) >> 4) * 20) + ((idx) & 15)] = (val)
#define LDSRC(P, a0, a1, a2, a3)                      \
    a0 = *(const f32x4*)&(P)[u*20];                   \
    a1 = *(const f32x4*)&(P)[u*20 + 4];               \
    a2 = *(const f32x4*)&(P)[u*20 + 8];               \
    a3 = *(const f32x4*)&(P)[u*20 + 12];

// partial dot of 16 consecutive k (lane u covers k=u*16..u*16+15) vs bf16 row
__device__ __forceinline__ float dotpart(const bf16* __restrict__ wrow, int u,
    f32x4 s0, f32x4 s1, f32x4 s2, f32x4 s3)
{
    const bf16x8 w0 = *(const bf16x8*)(wrow + u*16);
    const bf16x8 w1 = *(const bf16x8*)(wrow + u*16 + 8);
    float a = 0.f;
#pragma unroll
    for (int j = 0; j < 4; ++j) a += (float)w0[j]   * s0[j];
#pragma unroll
    for (int j = 0; j < 4; ++j) a += (float)w0[4+j] * s1[j];
#pragma unroll
    for (int j = 0; j < 4; ++j) a += (float)w1[j]   * s2[j];
#pragma unroll
    for (int j = 0; j < 4; ++j) a += (float)w1[4+j] * s3[j];
    return a;
}
__device__ __forceinline__ float red16(float a) {
#pragma unroll
    for (int m = 1; m < 16; m <<= 1) a += __shfl_xor(a, m);
    return a;
}

// ---------------- K0: prep (slots copy + bf16 weight conversions) ----------------
__global__ __launch_bounds__(256) void k_prep(
    const float* __restrict__ slots_in, const float* __restrict__ Wq,
    const float* __restrict__ Wv, const float* __restrict__ W_ih,
    const float* __restrict__ W_hh, const float* __restrict__ W1,
    const float* __restrict__ W2, const float* __restrict__ Wk,
    float* __restrict__ slots, bf16* __restrict__ Wq_b, bf16* __restrict__ Wv_b,
    bf16* __restrict__ Wih_b, bf16* __restrict__ Whh_b,
    bf16* __restrict__ W1_b, bf16* __restrict__ W2_b, bf16* __restrict__ WkT_b)
{
    const int i = blockIdx.x * 256 + threadIdx.x;
    if      (i <  65536) { slots[i] = slots_in[i]; }
    else if (i < 131072) { int j = i -  65536; Wq_b[j]  = (bf16)Wq[j]; }
    else if (i < 196608) { int j = i - 131072; Wv_b[j]  = (bf16)Wv[j]; }
    else if (i < 393216) { int j = i - 196608; Wih_b[j] = (bf16)W_ih[j]; }
    else if (i < 589824) { int j = i - 393216; Whh_b[j] = (bf16)W_hh[j]; }
    else if (i < 720896) { int j = i - 589824; W1_b[j]  = (bf16)W1[j]; }
    else if (i < 851968) { int j = i - 720896; W2_b[j]  = (bf16)W2[j]; }
    else if (i < 917504) { int j = i - 851968; WkT_b[j] = (bf16)Wk[(j & 255)*256 + (j >> 8)]; }
}

// ---------------- K1: LayerNorm(inputs) -> xln bf16 ----------------
__global__ __launch_bounds__(256) void k_ln_in(
    const float* __restrict__ x, const float* __restrict__ g,
    const float* __restrict__ b, bf16* __restrict__ xln)
{
    const int wave = threadIdx.x >> 6, lane = threadIdx.x & 63;
    const size_t row = (size_t)blockIdx.x * 4 + wave;
    const float* xr = x + row * 256 + lane * 4;
    f32x4 v = *(const f32x4*)xr;
    float s  = v[0] + v[1] + v[2] + v[3];
    float ss = v[0]*v[0] + v[1]*v[1] + v[2]*v[2] + v[3]*v[3];
#pragma unroll
    for (int m = 32; m >= 1; m >>= 1) { s += __shfl_xor(s, m); ss += __shfl_xor(ss, m); }
    const float mean = s * (1.f/256.f);
    const float var  = ss * (1.f/256.f) - mean*mean;
    const float rstd = rsqrtf(var + 1e-5f);
    const f32x4 gg = *(const f32x4*)(g + lane*4);
    const f32x4 bb = *(const f32x4*)(b + lane*4);
    bf16x4 o;
#pragma unroll
    for (int e = 0; e < 4; ++e) o[e] = (bf16)((v[e]-mean)*rstd*gg[e] + bb[e]);
    *(bf16x4*)(xln + row*256 + lane*4) = o;
}

// ---------------- K_q0: seed q2 for iteration 0; zero den. grid 256 ----------------
__global__ __launch_bounds__(512) void k_q0(
    const float* __restrict__ slots, const bf16* __restrict__ Wq_b,
    const bf16* __restrict__ WkT_b, const float* __restrict__ g_s,
    const float* __restrict__ b_s, float* __restrict__ q2buf,
    float* __restrict__ den)
{
    const int bs = blockIdx.x, tid = threadIdx.x;
    const int wv = tid >> 6, ln = tid & 63, gq = ln >> 4, u = ln & 15;
    __shared__ float HS[256], P0[320], P1[320], red[8];
    if (tid < 256) HS[tid] = slots[(size_t)bs*256 + tid];
    if (tid == 0) den[bs] = 0.f;
    __syncthreads();
    if (tid < 256) {
        const float v = HS[tid];
        float s1 = v, s2 = v*v;
#pragma unroll
        for (int m = 32; m >= 1; m >>= 1) { s1 += __shfl_xor(s1, m); s2 += __shfl_xor(s2, m); }
        if (ln == 0) { red[wv] = s1; red[4+wv] = s2; }
    }
    __syncthreads();
    if (tid < 256) {
        const float tot  = red[0]+red[1]+red[2]+red[3];
        const float tot2 = red[4]+red[5]+red[6]+red[7];
        const float mean = tot*(1.f/256.f);
        const float var  = tot2*(1.f/256.f) - mean*mean;
        const float rstd = rsqrtf(var + 1e-5f);
        PSTORE(P0, tid, (HS[tid]-mean)*rstd*g_s[tid] + b_s[tid]);
    }
    __syncthreads();
    {   // q = sln @ Wq^T * scale -> P1
        f32x4 a0,a1,a2,a3; LDSRC(P0,a0,a1,a2,a3);
#pragma unroll 2
        for (int i = 0; i < 8; ++i) {
            const int col = i*32 + wv*4 + gq;
            float a = red16(dotpart(Wq_b + (size_t)col*256, u, a0,a1,a2,a3));
            if (u == 0) PSTORE(P1, col, a * 0.0625f);
        }
    }
    __syncthreads();
    {   // q2 = q @ Wk -> global
        f32x4 a0,a1,a2,a3; LDSRC(P1,a0,a1,a2,a3);
#pragma unroll 2
        for (int i = 0; i < 8; ++i) {
            const int col = i*32 + wv*4 + gq;
            float a = red16(dotpart(WkT_b + (size_t)col*256, u, a0,a1,a2,a3));
            if (u == 0) q2buf[(size_t)bs*256 + col] = a;
        }
    }
}

// ---------------- K_attn1: logits = q2·xln[t]; softmax over s; a->abuf ----------------
__global__ __launch_bounds__(256) void k_attn1(
    const bf16* __restrict__ xln, const float* __restrict__ q2buf,
    bf16* __restrict__ abuf, float* __restrict__ den,
    float* __restrict__ logits_out, int write_logits)
{
    const int chunk = blockIdx.x, b = blockIdx.y, tid = threadIdx.x;
    __shared__ __align__(16) float q2s[8][256];
    {
        f32x4 v0 = *(const f32x4*)(q2buf + (size_t)b*2048 + tid*8);
        f32x4 v1 = *(const f32x4*)(q2buf + (size_t)b*2048 + tid*8 + 4);
        *(f32x4*)&q2s[tid >> 5][(tid & 31)*8]     = v0;
        *(f32x4*)&q2s[tid >> 5][(tid & 31)*8 + 4] = v1;
    }
    __syncthreads();

    const int t = chunk*256 + tid;
    const bf16* xp = xln + (size_t)(b*4096 + t)*256;
    float acc[8] = {0,0,0,0,0,0,0,0};
    for (int c8 = 0; c8 < 32; ++c8) {
        bf16x8 x8 = *(const bf16x8*)(xp + c8*8);
        float xf[8];
#pragma unroll
        for (int e = 0; e < 8; ++e) xf[e] = (float)x8[e];
#pragma unroll
        for (int s = 0; s < 8; ++s) {
            f32x4 qa = *(const f32x4*)&q2s[s][c8*8];
            f32x4 qb = *(const f32x4*)&q2s[s][c8*8 + 4];
#pragma unroll
            for (int e = 0; e < 4; ++e) acc[s] += qa[e]*xf[e] + qb[e]*xf[4+e];
        }
    }
    float mx = acc[0];
#pragma unroll
    for (int s = 1; s < 8; ++s) mx = fmaxf(mx, acc[s]);
    float a[8], sum = 0.f;
#pragma unroll
    for (int s = 0; s < 8; ++s) { a[s] = expf(acc[s] - mx); sum += a[s]; }
    const float inv = 1.f/sum;
#pragma unroll
    for (int s = 0; s < 8; ++s) a[s] = a[s]*inv + 1e-8f;

#pragma unroll
    for (int s = 0; s < 8; ++s)
        abuf[(size_t)(b*8 + s)*4096 + t] = (bf16)a[s];
    if (write_logits) {
#pragma unroll
        for (int s = 0; s < 8; ++s)
            logits_out[(size_t)(b*8 + s)*4096 + t] = acc[s];
    }
#pragma unroll
    for (int s = 0; s < 8; ++s) {
        float v = a[s];
#pragma unroll
        for (int m = 32; m >= 1; m >>= 1) v += __shfl_xor(v, m);
        if ((tid & 63) == 0) atomicAdd(&den[b*8 + s], v);
    }
}

// ---------------- K_attn2: numpart[b][chunk][s][c] = sum_t a[s][t]*xln[t][c] ----------------
__global__ __launch_bounds__(256) void k_attn2(
    const bf16* __restrict__ xln, const bf16* __restrict__ abuf,
    float* __restrict__ numpart)
{
    const int chunk = blockIdx.x, b = blockIdx.y, tid = threadIdx.x;
    __shared__ float alds[8][132];
    for (int i = tid; i < 1024; i += 256)
        alds[i >> 7][i & 127] = (float)abuf[(size_t)(b*8 + (i >> 7))*4096 + chunk*128 + (i & 127)];
    __syncthreads();

    const int s2 = tid >> 5, u = tid & 31;
    float nacc[8] = {0,0,0,0,0,0,0,0};
    const bf16* xp = xln + (size_t)(b*4096 + chunk*128)*256 + u*8;
#pragma unroll 4
    for (int t = 0; t < 128; ++t) {
        bf16x8 x8 = *(const bf16x8*)(xp + (size_t)t*256);
        const float a = alds[s2][t];
#pragma unroll
        for (int j = 0; j < 8; ++j) nacc[j] += a * (float)x8[j];
    }
    float* np = numpart + (((size_t)b*32 + chunk)*8 + s2)*256 + u*8;
    *(f32x4*)np       = (f32x4){nacc[0], nacc[1], nacc[2], nacc[3]};
    *(f32x4*)(np + 4) = (f32x4){nacc[4], nacc[5], nacc[6], nacc[7]};
}

// ---------------- K_attnsw: attn_sw = (softmax+eps)/den ----------------
__global__ __launch_bounds__(256) void k_attnsw(
    const float* __restrict__ logits, const float* __restrict__ den,
    float* __restrict__ attn_out)
{
    const int chunk = blockIdx.x, b = blockIdx.y;
    const int t = chunk*256 + threadIdx.x;
    float l[8];
#pragma unroll
    for (int s = 0; s < 8; ++s) l[s] = logits[(size_t)(b*8 + s)*4096 + t];
    float mx = l[0];
#pragma unroll
    for (int s = 1; s < 8; ++s) mx = fmaxf(mx, l[s]);
    float e[8], sum = 0.f;
#pragma unroll
    for (int s = 0; s < 8; ++s) { e[s] = expf(l[s] - mx); sum += e[s]; }
    const float inv = 1.f/sum;
#pragma unroll
    for (int s = 0; s < 8; ++s)
        attn_out[(size_t)(b*8 + s)*4096 + t] = (e[s]*inv + 1e-8f) / den[b*8 + s];
}

// ---------------- K_slot: per-row slot chain; wave-K GEMVs on bf16 weights ----
// grid 256 (one block per (b,s) row), 512 threads.
__global__ __launch_bounds__(512) void k_slot(
    const float* __restrict__ numpart, float* __restrict__ den,
    float* __restrict__ slots,
    const bf16* __restrict__ Wv_b, const bf16* __restrict__ Wih_b,
    const bf16* __restrict__ Whh_b,
    const float* __restrict__ b_ih, const float* __restrict__ b_hh,
    const float* __restrict__ g_m, const float* __restrict__ b_m,
    const bf16* __restrict__ W1_b, const float* __restrict__ b1,
    const bf16* __restrict__ W2_b, const float* __restrict__ b2,
    const bf16* __restrict__ Wq_b, const bf16* __restrict__ WkT_b,
    const float* __restrict__ g_s, const float* __restrict__ b_s,
    float* __restrict__ q2buf, float* __restrict__ out_slots, int last)
{
    const int bs = blockIdx.x, b = bs >> 3, s = bs & 7;
    const int tid = threadIdx.x;
    const int wv = tid >> 6, ln = tid & 63, gq = ln >> 4, u = ln & 15;
    __shared__ float HS[256], hpr[256], G[6][256];
    __shared__ float P0[320], P1[320], P2[320];
    __shared__ float red[8];
    __shared__ float dsc;

    // ---- stage A: yn = sum_chunk numpart ; HS ; den snapshot+clear ----
    {
        const int h = tid >> 8, d2 = tid & 255;
        float a = 0.f;
        const float* np = numpart + (((size_t)b*32 + h*16)*8 + s)*256 + d2;
#pragma unroll 4
        for (int c = 0; c < 16; ++c) a += np[(size_t)c*2048];
        G[h][d2] = a;
        if (tid < 256) HS[tid] = slots[(size_t)bs*256 + tid];
        if (tid == 0) { dsc = den[bs]; den[bs] = 0.f; }
    }
    __syncthreads();
    if (tid < 256) {
        PSTORE(P0, tid, G[0][tid] + G[1][tid]);   // yn padded
        PSTORE(P1, tid, HS[tid]);                  // HS padded
    }
    __syncthreads();

    // ---- upd = (yn @ Wv^T) / den -> P2 ----
    {
        f32x4 y0,y1,y2,y3; LDSRC(P0,y0,y1,y2,y3);
        const float inv = 1.f / dsc;
#pragma unroll 2
        for (int i = 0; i < 8; ++i) {
            const int col = i*32 + wv*4 + gq;
            float a = red16(dotpart(Wv_b + (size_t)col*256, u, y0,y1,y2,y3));
            if (u == 0) PSTORE(P2, col, a * inv);
        }
    }
    __syncthreads();

    // ---- gates: 1536 cols. col<768: upd@Wih ; else HS@Whh -> G[0..5] ----
    {
        f32x4 u0,u1,u2,u3; LDSRC(P2,u0,u1,u2,u3);
        f32x4 h0,h1,h2,h3; LDSRC(P1,h0,h1,h2,h3);
#pragma unroll 4
        for (int i = 0; i < 48; ++i) {
            const int col = i*32 + wv*4 + gq;
            float a;
            int g, dd;
            if (col < 768) {
                a = red16(dotpart(Wih_b + (size_t)col*256, u, u0,u1,u2,u3)) + b_ih[col];
                g = col >> 8; dd = col & 255;
            } else {
                const int ch = col - 768;
                a = red16(dotpart(Whh_b + (size_t)ch*256, u, h0,h1,h2,h3)) + b_hh[ch];
                g = 3 + (ch >> 8); dd = ch & 255;
            }
            if (u == 0) G[g][dd] = a;
        }
    }
    __syncthreads();

    // ---- GRU -> hpr ----
    if (tid < 256) {
        const float r = 1.f/(1.f + expf(-(G[0][tid] + G[3][tid])));
        const float z = 1.f/(1.f + expf(-(G[1][tid] + G[4][tid])));
        const float n = tanhf(G[2][tid] + r*G[5][tid]);
        hpr[tid] = (1.f - z)*n + z*HS[tid];
    }
    __syncthreads();

    // ---- LN_m -> P0 (hln) ----
    if (tid < 256) {
        const float v = hpr[tid];
        float s1 = v, s2 = v*v;
#pragma unroll
        for (int m = 32; m >= 1; m >>= 1) { s1 += __shfl_xor(s1, m); s2 += __shfl_xor(s2, m); }
        if (ln == 0) { red[wv] = s1; red[4+wv] = s2; }
    }
    __syncthreads();
    if (tid < 256) {
        const float tot  = red[0]+red[1]+red[2]+red[3];
        const float tot2 = red[4]+red[5]+red[6]+red[7];
        const float mean = tot*(1.f/256.f);
        const float var  = tot2*(1.f/256.f) - mean*mean;
        const float rstd = rsqrtf(var + 1e-5f);
        PSTORE(P0, tid, (hpr[tid]-mean)*rstd*g_m[tid] + b_m[tid]);
    }
    __syncthreads();

    // ---- mlp1: hid = relu(hln@W1^T + b1) -> P1 (lo), P2 (hi) ----
    {
        f32x4 a0,a1,a2,a3; LDSRC(P0,a0,a1,a2,a3);
#pragma unroll 4
        for (int i = 0; i < 16; ++i) {
            const int col = i*32 + wv*4 + gq;
            float a = red16(dotpart(W1_b + (size_t)col*256, u, a0,a1,a2,a3)) + b1[col];
            a = fmaxf(a, 0.f);
            if (u == 0) {
                if (col < 256) PSTORE(P1, col, a);
                else           PSTORE(P2, col - 256, a);
            }
        }
    }
    __syncthreads();

    // ---- mlp2: slots' = hpr + hid@W2^T + b2 -> HS + global ----
    {
        f32x4 l0,l1,l2,l3; LDSRC(P1,l0,l1,l2,l3);
        f32x4 m0,m1,m2,m3; LDSRC(P2,m0,m1,m2,m3);
#pragma unroll 2
        for (int i = 0; i < 8; ++i) {
            const int col = i*32 + wv*4 + gq;
            const bf16* wr = W2_b + (size_t)col*512;
            float a = dotpart(wr, u, l0,l1,l2,l3) + dotpart(wr + 256, u, m0,m1,m2,m3);
            a = red16(a);
            if (u == 0) {
                const float val = hpr[col] + a + b2[col];
                HS[col] = val;
                slots[(size_t)bs*256 + col] = val;
                if (last) out_slots[(size_t)bs*256 + col] = val;
            }
        }
    }
    __syncthreads();
    if (last) return;

    // ---- LN_s -> P0 (sln) ----
    if (tid < 256) {
        const float v = HS[tid];
        float s1 = v, s2 = v*v;
#pragma unroll
        for (int m = 32; m >= 1; m >>= 1) { s1 += __shfl_xor(s1, m); s2 += __shfl_xor(s2, m); }
        if (ln == 0) { red[wv] = s1; red[4+wv] = s2; }
    }
    __syncthreads();
    if (tid < 256) {
        const float tot  = red[0]+red[1]+red[2]+red[3];
        const float tot2 = red[4]+red[5]+red[6]+red[7];
        const float mean = tot*(1.f/256.f);
        const float var  = tot2*(1.f/256.f) - mean*mean;
        const float rstd = rsqrtf(var + 1e-5f);
        PSTORE(P0, tid, (HS[tid]-mean)*rstd*g_s[tid] + b_s[tid]);
    }
    __syncthreads();

    // ---- q = sln @ Wq^T * scale -> P1 ----
    {
        f32x4 a0,a1,a2,a3; LDSRC(P0,a0,a1,a2,a3);
#pragma unroll 2
        for (int i = 0; i < 8; ++i) {
            const int col = i*32 + wv*4 + gq;
            float a = red16(dotpart(Wq_b + (size_t)col*256, u, a0,a1,a2,a3));
            if (u == 0) PSTORE(P1, col, a * 0.0625f);
        }
    }
    __syncthreads();

    // ---- q2 = q @ Wk -> q2buf ----
    {
        f32x4 a0,a1,a2,a3; LDSRC(P1,a0,a1,a2,a3);
#pragma unroll 2
        for (int i = 0; i < 8; ++i) {
            const int col = i*32 + wv*4 + gq;
            float a = red16(dotpart(WkT_b + (size_t)col*256, u, a0,a1,a2,a3));
            if (u == 0) q2buf[(size_t)bs*256 + col] = a;
        }
    }
}

// ---------------- host ----------------
extern "C" void kernel_launch(void* const* d_in, const int* in_sizes, int n_in,
                              void* d_out, int out_size, void* d_ws, size_t ws_size,
                              hipStream_t stream)
{
    const float* x        = (const float*)d_in[0];
    const float* slots_in = (const float*)d_in[1];
    const float* ln_in_g  = (const float*)d_in[2];
    const float* ln_in_b  = (const float*)d_in[3];
    const float* ln_s_g   = (const float*)d_in[4];
    const float* ln_s_b   = (const float*)d_in[5];
    const float* ln_m_g   = (const float*)d_in[6];
    const float* ln_m_b   = (const float*)d_in[7];
    const float* Wq       = (const float*)d_in[8];
    const float* Wk       = (const float*)d_in[9];
    const float* Wv       = (const float*)d_in[10];
    const float* W_ih     = (const float*)d_in[11];
    const float* W_hh     = (const float*)d_in[12];
    const float* b_ih     = (const float*)d_in[13];
    const float* b_hh     = (const float*)d_in[14];
    const float* W1       = (const float*)d_in[15];
    const float* b1       = (const float*)d_in[16];
    const float* W2       = (const float*)d_in[17];
    const float* b2       = (const float*)d_in[18];

    float* out_slots  = (float*)d_out;
    float* out_logits = out_slots + 65536;
    float* out_attn   = out_logits + 1048576;

    char* w = (char*)d_ws;
    bf16*  xln     = (bf16*)w;   w += 67108864;   // [131072][256] bf16
    float* q2buf   = (float*)w;  w += 262144;
    bf16*  abuf    = (bf16*)w;   w += 2097152;
    float* slots   = (float*)w;  w += 262144;
    bf16*  Wq_b    = (bf16*)w;   w += 131072;
    bf16*  Wv_b    = (bf16*)w;   w += 131072;
    bf16*  Wih_b   = (bf16*)w;   w += 393216;
    bf16*  Whh_b   = (bf16*)w;   w += 393216;
    bf16*  W1_b    = (bf16*)w;   w += 262144;
    bf16*  W2_b    = (bf16*)w;   w += 262144;
    bf16*  WkT_b   = (bf16*)w;   w += 131072;
    float* numpart = (float*)w;  w += 8388608;    // [32 b][32 chunk][8 s][256 c] f32
    float* den     = (float*)w;  w += 4096;
    if ((size_t)(w - (char*)d_ws) > ws_size) return;  // ws too small: fail visibly

    k_prep<<<3584, 256, 0, stream>>>(slots_in, Wq, Wv, W_ih, W_hh, W1, W2, Wk,
                                     slots, Wq_b, Wv_b, Wih_b, Whh_b, W1_b, W2_b, WkT_b);
    k_ln_in<<<32768, 256, 0, stream>>>(x, ln_in_g, ln_in_b, xln);
    k_q0<<<256, 512, 0, stream>>>(slots, Wq_b, WkT_b, ln_s_g, ln_s_b, q2buf, den);

    for (int it = 0; it < 3; ++it) {
        const int last = (it == 2);
        k_attn1<<<dim3(16, 32), 256, 0, stream>>>(xln, q2buf, abuf, den, out_logits, last);
        k_attn2<<<dim3(32, 32), 256, 0, stream>>>(xln, abuf, numpart);
        if (last)
            k_attnsw<<<dim3(16, 32), 256, 0, stream>>>(out_logits, den, out_attn);
        k_slot<<<256, 512, 0, stream>>>(numpart, den, slots,
                                        Wv_b, Wih_b, Whh_b, b_ih, b_hh,
                                        ln_m_g, ln_m_b, W1_b, b1, W2_b, b2,
                                        Wq_b, WkT_b, ln_s_g, ln_s_b,
                                        q2buf, out_slots, last);
    }
}

// Round 7
// 377.438 us; speedup vs baseline: 1.7816x; 1.1900x over previous
//
#include <hip/hip_runtime.h>
#include <cstdint>
#include <cstddef>

typedef __bf16 bf16;
typedef float  f32x4  __attribute__((ext_vector_type(4)));
typedef __bf16 bf16x8 __attribute__((ext_vector_type(8)));
typedef __bf16 bf16x4 __attribute__((ext_vector_type(4)));

// ---------------- K0: prep (slots copy + bf16 TRANSPOSED weights WT[k][col]) ----
__global__ __launch_bounds__(256) void k_prep(
    const float* __restrict__ slots_in, const float* __restrict__ Wq,
    const float* __restrict__ Wv, const float* __restrict__ W_ih,
    const float* __restrict__ W_hh, const float* __restrict__ W1,
    const float* __restrict__ W2, const float* __restrict__ Wk,
    float* __restrict__ slots, bf16* __restrict__ WvT, bf16* __restrict__ WgT,
    bf16* __restrict__ W1T, bf16* __restrict__ W2T,
    bf16* __restrict__ WqT, bf16* __restrict__ Wk_b)
{
    const int i = blockIdx.x * 256 + threadIdx.x;
    if      (i <  65536) { slots[i] = slots_in[i]; }
    else if (i < 131072) { int j = i -  65536; int k = j >> 8, c = j & 255;
                           WvT[j] = (bf16)Wv[c*256 + k]; }
    else if (i < 524288) { int j = i - 131072; int k = j / 1536, c = j - k*1536;
                           WgT[j] = (bf16)((c < 768) ? W_ih[c*256 + k] : W_hh[(c-768)*256 + k]); }
    else if (i < 655360) { int j = i - 524288; int k = j >> 9, c = j & 511;
                           W1T[j] = (bf16)W1[c*256 + k]; }
    else if (i < 786432) { int j = i - 655360; int k = j >> 8, c = j & 255;
                           W2T[j] = (bf16)W2[c*512 + k]; }
    else if (i < 851968) { int j = i - 786432; int k = j >> 8, c = j & 255;
                           WqT[j] = (bf16)Wq[c*256 + k]; }
    else if (i < 917504) { int j = i - 851968; Wk_b[j] = (bf16)Wk[j]; }
}

// ---------------- K1: LayerNorm(inputs) -> xln bf16 ----------------
__global__ __launch_bounds__(256) void k_ln_in(
    const float* __restrict__ x, const float* __restrict__ g,
    const float* __restrict__ b, bf16* __restrict__ xln)
{
    const int wave = threadIdx.x >> 6, lane = threadIdx.x & 63;
    const size_t row = (size_t)blockIdx.x * 4 + wave;
    const float* xr = x + row * 256 + lane * 4;
    f32x4 v = *(const f32x4*)xr;
    float s  = v[0] + v[1] + v[2] + v[3];
    float ss = v[0]*v[0] + v[1]*v[1] + v[2]*v[2] + v[3]*v[3];
#pragma unroll
    for (int m = 32; m >= 1; m >>= 1) { s += __shfl_xor(s, m); ss += __shfl_xor(ss, m); }
    const float mean = s * (1.f/256.f);
    const float var  = ss * (1.f/256.f) - mean*mean;
    const float rstd = rsqrtf(var + 1e-5f);
    const f32x4 gg = *(const f32x4*)(g + lane*4);
    const f32x4 bb = *(const f32x4*)(b + lane*4);
    bf16x4 o;
#pragma unroll
    for (int e = 0; e < 4; ++e) o[e] = (bf16)((v[e]-mean)*rstd*gg[e] + bb[e]);
    *(bf16x4*)(xln + row*256 + lane*4) = o;
}

// gemv partial: 8 cols/thread, KLEN k's starting at wp (stride LDW), src LDS broadcast
__device__ __forceinline__ void gemv8(const bf16* __restrict__ wp, int LDW,
                                      const float* __restrict__ sp, int klen4,
                                      float* __restrict__ ac)
{
#pragma unroll 8
    for (int k4 = 0; k4 < klen4; ++k4) {
        const f32x4 sv = *(const f32x4*)(sp + k4*4);
#pragma unroll
        for (int kk = 0; kk < 4; ++kk) {
            const bf16x8 w = *(const bf16x8*)(wp + (size_t)(k4*4+kk)*LDW);
#pragma unroll
            for (int j = 0; j < 8; ++j) ac[j] += sv[kk]*(float)w[j];
        }
    }
}

// ---------------- K_q0: seed q2 for iteration 0; zero den. grid 256 ----------------
__global__ __launch_bounds__(512) void k_q0(
    const float* __restrict__ slots, const bf16* __restrict__ WqT,
    const bf16* __restrict__ Wk_b, const float* __restrict__ g_s,
    const float* __restrict__ b_s, float* __restrict__ q2buf,
    float* __restrict__ den)
{
    const int bs = blockIdx.x, tid = threadIdx.x;
    __shared__ float HS[256], sln[256], qv[256], part[2048], red[8];
    if (tid < 256) HS[tid] = slots[(size_t)bs*256 + tid];
    if (tid == 0) den[bs] = 0.f;
    __syncthreads();
    if (tid < 256) {
        const float v = HS[tid];
        float s1 = v, s2 = v*v;
#pragma unroll
        for (int m = 32; m >= 1; m >>= 1) { s1 += __shfl_xor(s1, m); s2 += __shfl_xor(s2, m); }
        if ((tid & 63) == 0) { red[tid >> 6] = s1; red[4 + (tid >> 6)] = s2; }
    }
    __syncthreads();
    if (tid < 256) {
        const float mean = (red[0]+red[1]+red[2]+red[3])*(1.f/256.f);
        const float var  = (red[4]+red[5]+red[6]+red[7])*(1.f/256.f) - mean*mean;
        const float rstd = rsqrtf(var + 1e-5f);
        sln[tid] = (HS[tid]-mean)*rstd*g_s[tid] + b_s[tid];
    }
    __syncthreads();
    if (tid < 256) {   // q: NG=32, KS=8
        const int g8 = tid & 31, ks = tid >> 5;
        float ac[8] = {0,0,0,0,0,0,0,0};
        gemv8(WqT + (size_t)(ks*32)*256 + g8*8, 256, sln + ks*32, 8, ac);
#pragma unroll
        for (int j = 0; j < 8; ++j) part[ks*256 + g8*8 + j] = ac[j];
    }
    __syncthreads();
    if (tid < 256) {
        float a = 0.f;
#pragma unroll
        for (int k = 0; k < 8; ++k) a += part[k*256 + tid];
        qv[tid] = a * 0.0625f;
    }
    __syncthreads();
    if (tid < 256) {   // q2
        const int g8 = tid & 31, ks = tid >> 5;
        float ac[8] = {0,0,0,0,0,0,0,0};
        gemv8(Wk_b + (size_t)(ks*32)*256 + g8*8, 256, qv + ks*32, 8, ac);
#pragma unroll
        for (int j = 0; j < 8; ++j) part[ks*256 + g8*8 + j] = ac[j];
    }
    __syncthreads();
    if (tid < 256) {
        float a = 0.f;
#pragma unroll
        for (int k = 0; k < 8; ++k) a += part[k*256 + tid];
        q2buf[(size_t)bs*256 + tid] = a;
    }
}

// ---------------- K_attn1: logits = q2·xln[t]; softmax over s; a->abuf ----------------
__global__ __launch_bounds__(256) void k_attn1(
    const bf16* __restrict__ xln, const float* __restrict__ q2buf,
    bf16* __restrict__ abuf, float* __restrict__ den,
    float* __restrict__ logits_out, int write_logits)
{
    const int chunk = blockIdx.x, b = blockIdx.y, tid = threadIdx.x;
    __shared__ __align__(16) float q2s[8][256];
    {
        f32x4 v0 = *(const f32x4*)(q2buf + (size_t)b*2048 + tid*8);
        f32x4 v1 = *(const f32x4*)(q2buf + (size_t)b*2048 + tid*8 + 4);
        *(f32x4*)&q2s[tid >> 5][(tid & 31)*8]     = v0;
        *(f32x4*)&q2s[tid >> 5][(tid & 31)*8 + 4] = v1;
    }
    __syncthreads();

    const int t = chunk*256 + tid;
    const bf16* xp = xln + (size_t)(b*4096 + t)*256;
    float acc[8] = {0,0,0,0,0,0,0,0};
    for (int c8 = 0; c8 < 32; ++c8) {
        bf16x8 x8 = *(const bf16x8*)(xp + c8*8);
        float xf[8];
#pragma unroll
        for (int e = 0; e < 8; ++e) xf[e] = (float)x8[e];
#pragma unroll
        for (int s = 0; s < 8; ++s) {
            f32x4 qa = *(const f32x4*)&q2s[s][c8*8];
            f32x4 qb = *(const f32x4*)&q2s[s][c8*8 + 4];
#pragma unroll
            for (int e = 0; e < 4; ++e) acc[s] += qa[e]*xf[e] + qb[e]*xf[4+e];
        }
    }
    float mx = acc[0];
#pragma unroll
    for (int s = 1; s < 8; ++s) mx = fmaxf(mx, acc[s]);
    float a[8], sum = 0.f;
#pragma unroll
    for (int s = 0; s < 8; ++s) { a[s] = expf(acc[s] - mx); sum += a[s]; }
    const float inv = 1.f/sum;
#pragma unroll
    for (int s = 0; s < 8; ++s) a[s] = a[s]*inv + 1e-8f;

#pragma unroll
    for (int s = 0; s < 8; ++s)
        abuf[(size_t)(b*8 + s)*4096 + t] = (bf16)a[s];
    if (write_logits) {
#pragma unroll
        for (int s = 0; s < 8; ++s)
            logits_out[(size_t)(b*8 + s)*4096 + t] = acc[s];
    }
#pragma unroll
    for (int s = 0; s < 8; ++s) {
        float v = a[s];
#pragma unroll
        for (int m = 32; m >= 1; m >>= 1) v += __shfl_xor(v, m);
        if ((tid & 63) == 0) atomicAdd(&den[b*8 + s], v);
    }
}

// ---------------- K_attn2: numpart[b][chunk][s][c] = sum_t a[s][t]*xln[t][c] ----------------
__global__ __launch_bounds__(256) void k_attn2(
    const bf16* __restrict__ xln, const bf16* __restrict__ abuf,
    float* __restrict__ numpart)
{
    const int chunk = blockIdx.x, b = blockIdx.y, tid = threadIdx.x;
    __shared__ float alds[8][132];
    for (int i = tid; i < 1024; i += 256)
        alds[i >> 7][i & 127] = (float)abuf[(size_t)(b*8 + (i >> 7))*4096 + chunk*128 + (i & 127)];
    __syncthreads();

    const int s2 = tid >> 5, u = tid & 31;
    float nacc[8] = {0,0,0,0,0,0,0,0};
    const bf16* xp = xln + (size_t)(b*4096 + chunk*128)*256 + u*8;
#pragma unroll 4
    for (int t = 0; t < 128; ++t) {
        bf16x8 x8 = *(const bf16x8*)(xp + (size_t)t*256);
        const float a = alds[s2][t];
#pragma unroll
        for (int j = 0; j < 8; ++j) nacc[j] += a * (float)x8[j];
    }
    float* np = numpart + (((size_t)b*32 + chunk)*8 + s2)*256 + u*8;
    *(f32x4*)np       = (f32x4){nacc[0], nacc[1], nacc[2], nacc[3]};
    *(f32x4*)(np + 4) = (f32x4){nacc[4], nacc[5], nacc[6], nacc[7]};
}

// ---------------- K_attnsw: attn_sw = (softmax+eps)/den ----------------
__global__ __launch_bounds__(256) void k_attnsw(
    const float* __restrict__ logits, const float* __restrict__ den,
    float* __restrict__ attn_out)
{
    const int chunk = blockIdx.x, b = blockIdx.y;
    const int t = chunk*256 + threadIdx.x;
    float l[8];
#pragma unroll
    for (int s = 0; s < 8; ++s) l[s] = logits[(size_t)(b*8 + s)*4096 + t];
    float mx = l[0];
#pragma unroll
    for (int s = 1; s < 8; ++s) mx = fmaxf(mx, l[s]);
    float e[8], sum = 0.f;
#pragma unroll
    for (int s = 0; s < 8; ++s) { e[s] = expf(l[s] - mx); sum += e[s]; }
    const float inv = 1.f/sum;
#pragma unroll
    for (int s = 0; s < 8; ++s)
        attn_out[(size_t)(b*8 + s)*4096 + t] = (e[s]*inv + 1e-8f) / den[b*8 + s];
}

// ---------------- K_slot: per-row slot chain; broadcast-GEMV, no cross-lane ----
// grid 256 (one block per (b,s) row), 512 threads.
__global__ __launch_bounds__(512) void k_slot(
    const float* __restrict__ numpart, float* __restrict__ den,
    float* __restrict__ slots,
    const bf16* __restrict__ WvT, const bf16* __restrict__ WgT,
    const float* __restrict__ b_ih, const float* __restrict__ b_hh,
    const float* __restrict__ g_m, const float* __restrict__ b_m,
    const bf16* __restrict__ W1T, const float* __restrict__ b1,
    const bf16* __restrict__ W2T, const float* __restrict__ b2,
    const bf16* __restrict__ WqT, const bf16* __restrict__ Wk_b,
    const float* __restrict__ g_s, const float* __restrict__ b_s,
    float* __restrict__ q2buf, float* __restrict__ out_slots, int last)
{
    const int bs = blockIdx.x, b = bs >> 3, s = bs & 7;
    const int tid = threadIdx.x;
    __shared__ float HS[256], yn[256], upd_[256], G[1536], hpr[256];
    __shared__ float hln[256], hid[512], sln[256], qv[256];
    __shared__ float part[4096];
    __shared__ float red[8];
    __shared__ float dsc;

    // ---- stage A: yn = sum_chunk numpart ; HS ; den snapshot+clear ----
    {
        const int h = tid >> 8, d2 = tid & 255;
        float a = 0.f;
        const float* np = numpart + (((size_t)b*32 + h*16)*8 + s)*256 + d2;
#pragma unroll 8
        for (int c = 0; c < 16; ++c) a += np[(size_t)c*2048];
        part[h*256 + d2] = a;
        if (tid < 256) HS[tid] = slots[(size_t)bs*256 + tid];
        if (tid == 0) { dsc = den[bs]; den[bs] = 0.f; }
    }
    __syncthreads();
    if (tid < 256) yn[tid] = part[tid] + part[256 + tid];
    __syncthreads();

    // ---- upd = (yn @ Wv^T)/den : NG=32, KS=8 ----
    if (tid < 256) {
        const int g8 = tid & 31, ks = tid >> 5;
        float ac[8] = {0,0,0,0,0,0,0,0};
        gemv8(WvT + (size_t)(ks*32)*256 + g8*8, 256, yn + ks*32, 8, ac);
#pragma unroll
        for (int j = 0; j < 8; ++j) part[ks*256 + g8*8 + j] = ac[j];
    }
    __syncthreads();
    if (tid < 256) {
        float a = 0.f;
#pragma unroll
        for (int k = 0; k < 8; ++k) a += part[k*256 + tid];
        upd_[tid] = a / dsc;
    }
    __syncthreads();

    // ---- gates: fused [upd|HS] @ WgT (N=1536, KS=2) ----
    if (tid < 384) {
        const int g8 = tid % 192, ks = tid / 192;
        const int col = g8*8;
        const float* sp = ((col < 768) ? upd_ : HS) + ks*128;
        float ac[8] = {0,0,0,0,0,0,0,0};
        gemv8(WgT + (size_t)(ks*128)*1536 + col, 1536, sp, 32, ac);
#pragma unroll
        for (int j = 0; j < 8; ++j) part[ks*1536 + col + j] = ac[j];
    }
    __syncthreads();
    for (int t = tid; t < 1536; t += 512) {
        const float bias = (t < 768) ? b_ih[t] : b_hh[t - 768];
        G[t] = part[t] + part[1536 + t] + bias;
    }
    __syncthreads();

    // ---- GRU -> hpr ----
    if (tid < 256) {
        const float r = 1.f/(1.f + expf(-(G[tid]       + G[768  + tid])));
        const float z = 1.f/(1.f + expf(-(G[256 + tid] + G[1024 + tid])));
        const float n = tanhf(G[512 + tid] + r*G[1280 + tid]);
        hpr[tid] = (1.f - z)*n + z*HS[tid];
    }
    __syncthreads();

    // ---- LN_m -> hln ----
    if (tid < 256) {
        const float v = hpr[tid];
        float s1 = v, s2 = v*v;
#pragma unroll
        for (int m = 32; m >= 1; m >>= 1) { s1 += __shfl_xor(s1, m); s2 += __shfl_xor(s2, m); }
        if ((tid & 63) == 0) { red[tid >> 6] = s1; red[4 + (tid >> 6)] = s2; }
    }
    __syncthreads();
    if (tid < 256) {
        const float mean = (red[0]+red[1]+red[2]+red[3])*(1.f/256.f);
        const float var  = (red[4]+red[5]+red[6]+red[7])*(1.f/256.f) - mean*mean;
        const float rstd = rsqrtf(var + 1e-5f);
        hln[tid] = (hpr[tid]-mean)*rstd*g_m[tid] + b_m[tid];
    }
    __syncthreads();

    // ---- mlp1: hid = relu(hln@W1^T + b1) : NG=64, KS=8 ----
    {
        const int g8 = tid & 63, ks = tid >> 6;
        float ac[8] = {0,0,0,0,0,0,0,0};
        gemv8(W1T + (size_t)(ks*32)*512 + g8*8, 512, hln + ks*32, 8, ac);
#pragma unroll
        for (int j = 0; j < 8; ++j) part[ks*512 + g8*8 + j] = ac[j];
    }
    __syncthreads();
    {
        float a = b1[tid];
#pragma unroll
        for (int k = 0; k < 8; ++k) a += part[k*512 + tid];
        hid[tid] = fmaxf(a, 0.f);
    }
    __syncthreads();

    // ---- mlp2: slots' = hpr + hid@W2^T + b2 : NG=32, KS=16 (K=512) ----
    {
        const int g8 = tid & 31, ks = tid >> 5;
        float ac[8] = {0,0,0,0,0,0,0,0};
        gemv8(W2T + (size_t)(ks*32)*256 + g8*8, 256, hid + ks*32, 8, ac);
#pragma unroll
        for (int j = 0; j < 8; ++j) part[ks*256 + g8*8 + j] = ac[j];
    }
    __syncthreads();
    if (tid < 256) {
        float a = 0.f;
#pragma unroll
        for (int k = 0; k < 16; ++k) a += part[k*256 + tid];
        const float val = hpr[tid] + a + b2[tid];
        HS[tid] = val;
        slots[(size_t)bs*256 + tid] = val;
        if (last) out_slots[(size_t)bs*256 + tid] = val;
    }
    __syncthreads();
    if (last) return;

    // ---- LN_s -> sln ----
    if (tid < 256) {
        const float v = HS[tid];
        float s1 = v, s2 = v*v;
#pragma unroll
        for (int m = 32; m >= 1; m >>= 1) { s1 += __shfl_xor(s1, m); s2 += __shfl_xor(s2, m); }
        if ((tid & 63) == 0) { red[tid >> 6] = s1; red[4 + (tid >> 6)] = s2; }
    }
    __syncthreads();
    if (tid < 256) {
        const float mean = (red[0]+red[1]+red[2]+red[3])*(1.f/256.f);
        const float var  = (red[4]+red[5]+red[6]+red[7])*(1.f/256.f) - mean*mean;
        const float rstd = rsqrtf(var + 1e-5f);
        sln[tid] = (HS[tid]-mean)*rstd*g_s[tid] + b_s[tid];
    }
    __syncthreads();

    // ---- q = sln @ Wq^T * scale : NG=32, KS=8 ----
    if (tid < 256) {
        const int g8 = tid & 31, ks = tid >> 5;
        float ac[8] = {0,0,0,0,0,0,0,0};
        gemv8(WqT + (size_t)(ks*32)*256 + g8*8, 256, sln + ks*32, 8, ac);
#pragma unroll
        for (int j = 0; j < 8; ++j) part[ks*256 + g8*8 + j] = ac[j];
    }
    __syncthreads();
    if (tid < 256) {
        float a = 0.f;
#pragma unroll
        for (int k = 0; k < 8; ++k) a += part[k*256 + tid];
        qv[tid] = a * 0.0625f;
    }
    __syncthreads();

    // ---- q2 = q @ Wk : NG=32, KS=8 ----
    if (tid < 256) {
        const int g8 = tid & 31, ks = tid >> 5;
        float ac[8] = {0,0,0,0,0,0,0,0};
        gemv8(Wk_b + (size_t)(ks*32)*256 + g8*8, 256, qv + ks*32, 8, ac);
#pragma unroll
        for (int j = 0; j < 8; ++j) part[ks*256 + g8*8 + j] = ac[j];
    }
    __syncthreads();
    if (tid < 256) {
        float a = 0.f;
#pragma unroll
        for (int k = 0; k < 8; ++k) a += part[k*256 + tid];
        q2buf[(size_t)bs*256 + tid] = a;
    }
}

// ---------------- host ----------------
extern "C" void kernel_launch(void* const* d_in, const int* in_sizes, int n_in,
                              void* d_out, int out_size, void* d_ws, size_t ws_size,
                              hipStream_t stream)
{
    const float* x        = (const float*)d_in[0];
    const float* slots_in = (const float*)d_in[1];
    const float* ln_in_g  = (const float*)d_in[2];
    const float* ln_in_b  = (const float*)d_in[3];
    const float* ln_s_g   = (const float*)d_in[4];
    const float* ln_s_b   = (const float*)d_in[5];
    const float* ln_m_g   = (const float*)d_in[6];
    const float* ln_m_b   = (const float*)d_in[7];
    const float* Wq       = (const float*)d_in[8];
    const float* Wk       = (const float*)d_in[9];
    const float* Wv       = (const float*)d_in[10];
    const float* W_ih     = (const float*)d_in[11];
    const float* W_hh     = (const float*)d_in[12];
    const float* b_ih     = (const float*)d_in[13];
    const float* b_hh     = (const float*)d_in[14];
    const float* W1       = (const float*)d_in[15];
    const float* b1       = (const float*)d_in[16];
    const float* W2       = (const float*)d_in[17];
    const float* b2       = (const float*)d_in[18];

    float* out_slots  = (float*)d_out;
    float* out_logits = out_slots + 65536;
    float* out_attn   = out_logits + 1048576;

    char* w = (char*)d_ws;
    bf16*  xln     = (bf16*)w;   w += 67108864;   // [131072][256] bf16
    float* q2buf   = (float*)w;  w += 262144;
    bf16*  abuf    = (bf16*)w;   w += 2097152;
    float* slots   = (float*)w;  w += 262144;
    bf16*  WvT     = (bf16*)w;   w += 131072;
    bf16*  WgT     = (bf16*)w;   w += 786432;     // [256][1536]
    bf16*  W1T     = (bf16*)w;   w += 262144;     // [256][512]
    bf16*  W2T     = (bf16*)w;   w += 262144;     // [512][256]
    bf16*  WqT     = (bf16*)w;   w += 131072;
    bf16*  Wk_b    = (bf16*)w;   w += 131072;
    float* numpart = (float*)w;  w += 8388608;    // [32 b][32 chunk][8 s][256 c] f32
    float* den     = (float*)w;  w += 4096;
    if ((size_t)(w - (char*)d_ws) > ws_size) return;  // ws too small: fail visibly

    k_prep<<<3584, 256, 0, stream>>>(slots_in, Wq, Wv, W_ih, W_hh, W1, W2, Wk,
                                     slots, WvT, WgT, W1T, W2T, WqT, Wk_b);
    k_ln_in<<<32768, 256, 0, stream>>>(x, ln_in_g, ln_in_b, xln);
    k_q0<<<256, 512, 0, stream>>>(slots, WqT, Wk_b, ln_s_g, ln_s_b, q2buf, den);

    for (int it = 0; it < 3; ++it) {
        const int last = (it == 2);
        k_attn1<<<dim3(16, 32), 256, 0, stream>>>(xln, q2buf, abuf, den, out_logits, last);
        k_attn2<<<dim3(32, 32), 256, 0, stream>>>(xln, abuf, numpart);
        if (last)
            k_attnsw<<<dim3(16, 32), 256, 0, stream>>>(out_logits, den, out_attn);
        k_slot<<<256, 512, 0, stream>>>(numpart, den, slots,
                                        WvT, WgT, b_ih, b_hh,
                                        ln_m_g, ln_m_b, W1T, b1, W2T, b2,
                                        WqT, Wk_b, ln_s_g, ln_s_b,
                                        q2buf, out_slots, last);
    }
}